// Round 6
// baseline (82.651 us; speedup 1.0000x reference)
//
#include <hip/hip_runtime.h>

// out[row][k] = x[row][k]*Lambda[k] + sum_l B[k][l]*y[row][l]
// rows = 1,048,576, L = 32.  mfma_f32_16x16x32_bf16, D = out^T-chunked
// (R5 mapping: lane (r,h) holds out[row0+r][h*4+j (+16)] -> all VMEM 16B).
// R6 change: ONE-DEEP PREFETCH. R4/R5 iterated loads->waitcnt->compute->stores,
// so the data-wait was vmcnt(0), which also waits the PREVIOUS iteration's
// store acks (~1000cyc HBM round trip) -> latency-serialized at ~2.5 TB/s with
// all pipes idle. Prefetching tile t+1's loads before compute/store of t means
// the wait for t+1 leaves stores (and later loads) outstanding behind it:
// store acks never block, >=4KB reads stay in flight per wave.

typedef __attribute__((ext_vector_type(8))) short bf16x8;
typedef __attribute__((ext_vector_type(4))) float f32x4;

__device__ __forceinline__ short f2bf(float f) {
    union { float f; unsigned u; } v; v.f = f;
    unsigned r = v.u + 0x7fffu + ((v.u >> 16) & 1u);   // RNE (inputs finite)
    return (short)(r >> 16);
}

__global__ __launch_bounds__(256) void ax_bu_mfma(
    const float* __restrict__ x,
    const float* __restrict__ y,
    const float* __restrict__ Lam,
    const float* __restrict__ B,
    float* __restrict__ out,
    int ntiles)   // rows / 16
{
    const int lane = threadIdx.x & 63;
    const int gw = (blockIdx.x * (blockDim.x >> 6)) + (threadIdx.x >> 6);
    const int nwaves = gridDim.x * (blockDim.x >> 6);

    const int r = lane & 15;   // row-within-tile (D col)
    const int h = lane >> 4;   // octet selector

    // A-frags (B-matrix rows, hoisted): A[m=r][l=h*8+j] = B[r][h*8+j]
    bf16x8 ba0, ba1;
    {
        const float* b0 = B + r * 32 + h * 8;
        const float* b1 = B + (r + 16) * 32 + h * 8;
#pragma unroll
        for (int j = 0; j < 8; ++j) {
            ba0[j] = f2bf(b0[j]);
            ba1[j] = f2bf(b1[j]);
        }
    }
    // Lambda for channels this lane's C/D holds: k = h*4+j (+16)
    const float4 lam0 = *reinterpret_cast<const float4*>(Lam + h * 4);
    const float4 lam1 = *reinterpret_cast<const float4*>(Lam + 16 + h * 4);

    int t = gw;
    if (t >= ntiles) return;

    // ---- load tile t (prologue) ----
    float4 y0, y1, x0, x1;
    {
        const int row = (t << 4) + r;
        const float4* yp = reinterpret_cast<const float4*>(y + row * 32 + h * 8);
        y0 = yp[0]; y1 = yp[1];
        const float4* xp = reinterpret_cast<const float4*>(x + row * 32 + h * 4);
        x0 = xp[0]; x1 = xp[4];
    }

    while (true) {
        const int tn = t + nwaves;
        const bool more = (tn < ntiles);

        // ---- prefetch tile t+1 BEFORE compute/store of tile t ----
        float4 ny0, ny1, nx0, nx1;
        if (more) {
            const int row = (tn << 4) + r;
            const float4* yp = reinterpret_cast<const float4*>(y + row * 32 + h * 8);
            ny0 = yp[0]; ny1 = yp[1];
            const float4* xp = reinterpret_cast<const float4*>(x + row * 32 + h * 4);
            nx0 = xp[0]; nx1 = xp[4];
        }

        // ---- compute tile t ----
        bf16x8 yf;
        yf[0] = f2bf(y0.x); yf[1] = f2bf(y0.y); yf[2] = f2bf(y0.z); yf[3] = f2bf(y0.w);
        yf[4] = f2bf(y1.x); yf[5] = f2bf(y1.y); yf[6] = f2bf(y1.z); yf[7] = f2bf(y1.w);

        f32x4 c0, c1;
        c0[0] = x0.x * lam0.x; c0[1] = x0.y * lam0.y;
        c0[2] = x0.z * lam0.z; c0[3] = x0.w * lam0.w;
        c1[0] = x1.x * lam1.x; c1[1] = x1.y * lam1.y;
        c1[2] = x1.z * lam1.z; c1[3] = x1.w * lam1.w;

        c0 = __builtin_amdgcn_mfma_f32_16x16x32_bf16(ba0, yf, c0, 0, 0, 0);
        c1 = __builtin_amdgcn_mfma_f32_16x16x32_bf16(ba1, yf, c1, 0, 0, 0);

        const int row = (t << 4) + r;
        float4* op = reinterpret_cast<float4*>(out + row * 32 + h * 4);
        op[0] = make_float4(c0[0], c0[1], c0[2], c0[3]);
        op[4] = make_float4(c1[0], c1[1], c1[2], c1[3]);

        if (!more) break;
        y0 = ny0; y1 = ny1; x0 = nx0; x1 = nx1;
        t = tn;
    }
}

extern "C" void kernel_launch(void* const* d_in, const int* in_sizes, int n_in,
                              void* d_out, int out_size, void* d_ws, size_t ws_size,
                              hipStream_t stream) {
    const float* x   = (const float*)d_in[0];
    const float* y   = (const float*)d_in[1];
    const float* Lam = (const float*)d_in[2];
    const float* B   = (const float*)d_in[3];
    float* out = (float*)d_out;

    const int rows = in_sizes[0] / 32;       // 1,048,576
    const int ntiles = rows / 16;            // 65,536
    const int block = 256;                   // 4 waves
    int grid = 2048;                         // 8192 waves -> 8 tiles/wave
    if (grid * (block >> 6) > ntiles) grid = (ntiles + (block >> 6) - 1) / (block >> 6);

    ax_bu_mfma<<<grid, block, 0, stream>>>(x, y, Lam, B, out, ntiles);
}

// Round 7
// 68.599 us; speedup vs baseline: 1.2048x; 1.2048x over previous
//
#include <hip/hip_runtime.h>

// out[row][k] = x[row][k]*Lambda[k] + sum_l B[k][l]*y[row][l]
// rows = 1,048,576, L = 32.  mfma_f32_16x16x32_bf16, D = out^T-chunked:
// lane (r,h) holds out[row0+r][h*4+j (+16)] -> all VMEM 16B/lane.
// R7 change: NON-TEMPORAL output stores. R4-R6 all plateau at ~82us with
// FETCH_SIZE = exactly half the input bytes: the 134MB output stream
// allocates in L3 (256MB) and evicts half the 268MB input set. The output
// is never re-read -> caching it is pure pollution. `nt` stores keep L3
// for inputs; predicted FETCH -> <70MB, dur -> 60-72us.

typedef __attribute__((ext_vector_type(8))) short bf16x8;
typedef __attribute__((ext_vector_type(4))) float f32x4;

__device__ __forceinline__ short f2bf(float f) {
    union { float f; unsigned u; } v; v.f = f;
    unsigned r = v.u + 0x7fffu + ((v.u >> 16) & 1u);   // RNE (inputs finite)
    return (short)(r >> 16);
}

__global__ __launch_bounds__(256) void ax_bu_mfma(
    const float* __restrict__ x,
    const float* __restrict__ y,
    const float* __restrict__ Lam,
    const float* __restrict__ B,
    float* __restrict__ out,
    int ntiles)   // rows / 16
{
    const int lane = threadIdx.x & 63;
    const int gw = (blockIdx.x * (blockDim.x >> 6)) + (threadIdx.x >> 6);
    const int nwaves = gridDim.x * (blockDim.x >> 6);

    const int r = lane & 15;   // row-within-tile (D col)
    const int h = lane >> 4;   // octet selector

    // A-frags (B-matrix rows, hoisted): A[m=r][l=h*8+j] = B[r][h*8+j]
    bf16x8 ba0, ba1;
    {
        const float* b0 = B + r * 32 + h * 8;
        const float* b1 = B + (r + 16) * 32 + h * 8;
#pragma unroll
        for (int j = 0; j < 8; ++j) {
            ba0[j] = f2bf(b0[j]);
            ba1[j] = f2bf(b1[j]);
        }
    }
    // Lambda for channels this lane's C/D holds: k = h*4+j (+16)
    const float4 lam0 = *reinterpret_cast<const float4*>(Lam + h * 4);
    const float4 lam1 = *reinterpret_cast<const float4*>(Lam + 16 + h * 4);

    int t = gw;
    if (t >= ntiles) return;

    // ---- load tile t (prologue) ----
    float4 y0, y1, x0, x1;
    {
        const int row = (t << 4) + r;
        const float4* yp = reinterpret_cast<const float4*>(y + row * 32 + h * 8);
        y0 = yp[0]; y1 = yp[1];
        const float4* xp = reinterpret_cast<const float4*>(x + row * 32 + h * 4);
        x0 = xp[0]; x1 = xp[4];
    }

    while (true) {
        const int tn = t + nwaves;
        const bool more = (tn < ntiles);

        // ---- prefetch tile t+1 BEFORE compute/store of tile t ----
        float4 ny0, ny1, nx0, nx1;
        if (more) {
            const int row = (tn << 4) + r;
            const float4* yp = reinterpret_cast<const float4*>(y + row * 32 + h * 8);
            ny0 = yp[0]; ny1 = yp[1];
            const float4* xp = reinterpret_cast<const float4*>(x + row * 32 + h * 4);
            nx0 = xp[0]; nx1 = xp[4];
        }

        // ---- compute tile t ----
        bf16x8 yf;
        yf[0] = f2bf(y0.x); yf[1] = f2bf(y0.y); yf[2] = f2bf(y0.z); yf[3] = f2bf(y0.w);
        yf[4] = f2bf(y1.x); yf[5] = f2bf(y1.y); yf[6] = f2bf(y1.z); yf[7] = f2bf(y1.w);

        f32x4 c0, c1;
        c0[0] = x0.x * lam0.x; c0[1] = x0.y * lam0.y;
        c0[2] = x0.z * lam0.z; c0[3] = x0.w * lam0.w;
        c1[0] = x1.x * lam1.x; c1[1] = x1.y * lam1.y;
        c1[2] = x1.z * lam1.z; c1[3] = x1.w * lam1.w;

        c0 = __builtin_amdgcn_mfma_f32_16x16x32_bf16(ba0, yf, c0, 0, 0, 0);
        c1 = __builtin_amdgcn_mfma_f32_16x16x32_bf16(ba1, yf, c1, 0, 0, 0);

        const int row = (t << 4) + r;
        f32x4* op = reinterpret_cast<f32x4*>(out + row * 32 + h * 4);
        __builtin_nontemporal_store(c0, op);       // channels h*4..h*4+3
        __builtin_nontemporal_store(c1, op + 4);   // channels 16+h*4..+3

        if (!more) break;
        y0 = ny0; y1 = ny1; x0 = nx0; x1 = nx1;
        t = tn;
    }
}

extern "C" void kernel_launch(void* const* d_in, const int* in_sizes, int n_in,
                              void* d_out, int out_size, void* d_ws, size_t ws_size,
                              hipStream_t stream) {
    const float* x   = (const float*)d_in[0];
    const float* y   = (const float*)d_in[1];
    const float* Lam = (const float*)d_in[2];
    const float* B   = (const float*)d_in[3];
    float* out = (float*)d_out;

    const int rows = in_sizes[0] / 32;       // 1,048,576
    const int ntiles = rows / 16;            // 65,536
    const int block = 256;                   // 4 waves
    int grid = 2048;                         // 8192 waves -> 8 tiles/wave
    if (grid * (block >> 6) > ntiles) grid = (ntiles + (block >> 6) - 1) / (block >> 6);

    ax_bu_mfma<<<grid, block, 0, stream>>>(x, y, Lam, B, out, ntiles);
}